// Round 4
// baseline (1464.933 us; speedup 1.0000x reference)
//
#include <hip/hip_runtime.h>
#include <hip/hip_bf16.h>

#define N_NODES 100000
#define N_EDGES 3200000
#define IN_CH   128
#define HID     32
#define NB      512              // dst buckets for CSR build
#define NPB     196              // nodes per bucket (512*196 >= 100000)
#define MAXBE   8192             // LDS staging capacity per bucket (edges)

// ---------------------------------------------------------------------------
// Detect whether edge_index is int64 (odd 32-bit words all zero) or int32.
// ---------------------------------------------------------------------------
__global__ __launch_bounds__(256) void detect_idx(const int* __restrict__ ei,
                                                  int* __restrict__ flag) {
    __shared__ int nz;
    if (threadIdx.x == 0) nz = 0;
    __syncthreads();
    if (ei[2 * threadIdx.x + 1] != 0) atomicAdd(&nz, 1);
    __syncthreads();
    if (threadIdx.x == 0) flag[0] = (nz == 0) ? 1 : 0;
}

__device__ __forceinline__ int edge_at(const int* __restrict__ ei, int idx64,
                                       size_t pos) {
    if (idx64) return (int)((const long long*)ei)[pos];
    return ei[pos];
}

// ---------------------------------------------------------------------------
// Degree / normalization
// ---------------------------------------------------------------------------
__global__ __launch_bounds__(256) void zero_deg(int* __restrict__ deg) {
    int i = blockIdx.x * 256 + threadIdx.x;
    if (i < N_NODES) deg[i] = 0;
}

__global__ __launch_bounds__(256) void count_deg(const int* __restrict__ ei,
                                                 const int* __restrict__ flag,
                                                 int* __restrict__ deg) {
    int i = blockIdx.x * 256 + threadIdx.x;
    if (i >= N_EDGES) return;
    int idx64 = flag[0];
    int d = edge_at(ei, idx64, (size_t)N_EDGES + i);   // dst = edge_index[1]
    atomicAdd(&deg[d], 1);
}

__global__ __launch_bounds__(256) void make_dinv(const int* __restrict__ deg,
                                                 float* __restrict__ dinv) {
    int i = blockIdx.x * 256 + threadIdx.x;
    if (i < N_NODES) dinv[i] = rsqrtf((float)(deg[i] + 1));  // +1 self-loop
}

// --- exclusive scan of deg -> rowptr (3 kernels) ---------------------------
__global__ __launch_bounds__(256) void scan_s1(const int* __restrict__ deg,
                                               int* __restrict__ rowptr,
                                               int* __restrict__ partials) {
    __shared__ int tmp[256];
    int t = threadIdx.x;
    int base = blockIdx.x * 1024;
    int v[4];
#pragma unroll
    for (int j = 0; j < 4; ++j) {
        int idx = base + t * 4 + j;
        v[j] = (idx < N_NODES) ? deg[idx] : 0;
    }
    int s = v[0] + v[1] + v[2] + v[3];
    tmp[t] = s;
    __syncthreads();
    for (int off = 1; off < 256; off <<= 1) {
        int x = 0;
        if (t >= off) x = tmp[t - off];
        __syncthreads();
        if (t >= off) tmp[t] += x;
        __syncthreads();
    }
    int run = tmp[t] - s;
#pragma unroll
    for (int j = 0; j < 4; ++j) {
        int idx = base + t * 4 + j;
        if (idx < N_NODES) rowptr[idx] = run;
        run += v[j];
    }
    if (t == 255) partials[blockIdx.x] = tmp[255];
}

__global__ __launch_bounds__(128) void scan_s2(int* __restrict__ partials) {
    __shared__ int tmp[128];
    int t = threadIdx.x;
    int v = (t < 98) ? partials[t] : 0;
    tmp[t] = v;
    __syncthreads();
    for (int off = 1; off < 128; off <<= 1) {
        int x = 0;
        if (t >= off) x = tmp[t - off];
        __syncthreads();
        if (t >= off) tmp[t] += x;
        __syncthreads();
    }
    if (t < 98) partials[t] = tmp[t] - v;
}

__global__ __launch_bounds__(256) void scan_s3(int* __restrict__ rowptr,
                                               const int* __restrict__ partials) {
    int i = blockIdx.x * 256 + threadIdx.x;
    if (i < N_NODES) rowptr[i] += partials[i >> 10];
    if (i == N_NODES) rowptr[N_NODES] = N_EDGES;
}

// ---------------------------------------------------------------------------
// Bucket pass: bucket b = contiguous node range [b*NPB, (b+1)*NPB), so
// bucket base offsets come straight from rowptr — no extra histogram.
// ---------------------------------------------------------------------------
__global__ __launch_bounds__(256) void bcur_init(const int* __restrict__ rowptr,
                                                 int* __restrict__ bcur) {
    int b = blockIdx.x * 256 + threadIdx.x;
    if (b < NB) {
        int n0 = b * NPB;
        if (n0 > N_NODES) n0 = N_NODES;
        bcur[b] = rowptr[n0];
    }
}

// scatter edges into dst-bucket-partitioned array, 4 B packed (s<<8)|dloc.
// writes within a bucket land at consecutive positions -> line locality.
__global__ __launch_bounds__(256) void bucket_scatter(
    const int* __restrict__ ei,
    const int* __restrict__ flag,
    int* __restrict__ bcur,
    unsigned int* __restrict__ ebuf) {
    int i = blockIdx.x * 256 + threadIdx.x;
    if (i >= N_EDGES) return;
    int idx64 = flag[0];
    unsigned int s = (unsigned int)edge_at(ei, idx64, (size_t)i);
    unsigned int d = (unsigned int)edge_at(ei, idx64, (size_t)N_EDGES + i);
    unsigned int b = d / NPB;          // compile-time const -> magic multiply
    unsigned int dloc = d - b * NPB;   // < 196 < 256
    int pos = atomicAdd(&bcur[b], 1);
    ebuf[pos] = (s << 8) | dloc;
}

// per-bucket CSR fill: scatter inside LDS, copy out coalesced.
__global__ __launch_bounds__(256) void fill_csr2(
    const int* __restrict__ rowptr,
    const unsigned int* __restrict__ ebuf,
    int* __restrict__ col) {
    __shared__ int lcur[NPB];
    __shared__ int lbuf[MAXBE];
    int b = blockIdx.x;
    int n0 = b * NPB;        if (n0 > N_NODES) n0 = N_NODES;
    int n1 = n0 + NPB;       if (n1 > N_NODES) n1 = N_NODES;
    int E0 = rowptr[n0];
    int E1 = rowptr[n1];
    int nn = n1 - n0;
    for (int j = threadIdx.x; j < nn; j += 256)
        lcur[j] = rowptr[n0 + j] - E0;
    __syncthreads();
    int sz = E1 - E0;
    if (sz <= MAXBE) {
        for (int i = E0 + threadIdx.x; i < E1; i += 256) {
            unsigned int e = ebuf[i];
            int p = atomicAdd(&lcur[e & 255u], 1);
            lbuf[p] = (int)(e >> 8);
        }
        __syncthreads();
        for (int j = threadIdx.x; j < sz; j += 256)
            col[E0 + j] = lbuf[j];
    } else {  // overflow fallback (statistically unreachable for uniform dst)
        for (int i = E0 + threadIdx.x; i < E1; i += 256) {
            unsigned int e = ebuf[i];
            int p = atomicAdd(&lcur[e & 255u], 1);
            col[E0 + p] = (int)(e >> 8);
        }
    }
}

// ---------------------------------------------------------------------------
// GEMM1: h1s[n][c] = (sum_k x[n][k] * W1[k][c]) * dinv[n]
// ---------------------------------------------------------------------------
__global__ __launch_bounds__(256) void gemm1_scale(
    const float* __restrict__ x,
    const float* __restrict__ W1,
    const float* __restrict__ dinv,
    float* __restrict__ h1s) {
    __shared__ float w[IN_CH * HID];   // 16 KB
    for (int i = threadIdx.x; i < IN_CH * HID; i += 256)
        w[i] = W1[i];
    __syncthreads();

    int node = blockIdx.x * 8 + (threadIdx.x >> 5);
    int c    = threadIdx.x & 31;
    if (node >= N_NODES) return;

    const float4* xr = reinterpret_cast<const float4*>(x + (size_t)node * IN_CH);
    float acc = 0.0f;
#pragma unroll
    for (int k4 = 0; k4 < IN_CH / 4; ++k4) {
        float4 v = xr[k4];
        acc += v.x * w[(k4 * 4 + 0) * HID + c]
             + v.y * w[(k4 * 4 + 1) * HID + c]
             + v.z * w[(k4 * 4 + 2) * HID + c]
             + v.w * w[(k4 * 4 + 3) * HID + c];
    }
    h1s[(size_t)node * HID + c] = acc * dinv[node];
}

// ---------------------------------------------------------------------------
// Layer-1 aggregate, fused: gather-sum + relu + gemm2 (lane shuffles) -> h3s
// ---------------------------------------------------------------------------
__global__ __launch_bounds__(256) void aggregate1(
    const int* __restrict__ rowptr,
    const int* __restrict__ col,
    const float* __restrict__ h1s,
    const float* __restrict__ dinv,
    const float* __restrict__ b1,
    const float* __restrict__ W2,
    float* __restrict__ h3s) {
    __shared__ float w2s[HID * HID];   // 4 KB
    for (int i = threadIdx.x; i < HID * HID; i += 256)
        w2s[i] = W2[i];
    __syncthreads();

    int node = blockIdx.x * 8 + (threadIdx.x >> 5);
    int c    = threadIdx.x & 31;
    if (node >= N_NODES) return;

    int e0 = rowptr[node];
    int e1 = rowptr[node + 1];
    float a0 = h1s[(size_t)node * HID + c];  // self-loop
    float a1 = 0.f, a2 = 0.f, a3 = 0.f;
    int e = e0;
    for (; e + 4 <= e1; e += 4) {
        int s0 = col[e], s1 = col[e + 1], s2 = col[e + 2], s3 = col[e + 3];
        a0 += h1s[(size_t)s0 * HID + c];
        a1 += h1s[(size_t)s1 * HID + c];
        a2 += h1s[(size_t)s2 * HID + c];
        a3 += h1s[(size_t)s3 * HID + c];
    }
    for (; e < e1; ++e)
        a1 += h1s[(size_t)col[e] * HID + c];

    float dn = dinv[node];
    float h2v = ((a0 + a1) + (a2 + a3)) * dn + b1[c];
    h2v = h2v > 0.0f ? h2v : 0.0f;

    float acc2 = 0.0f;
#pragma unroll
    for (int k = 0; k < HID; ++k)
        acc2 += __shfl(h2v, k, 32) * w2s[k * HID + c];

    h3s[(size_t)node * HID + c] = acc2 * dn;
}

// ---------------------------------------------------------------------------
// Layer-2 aggregate, fused epilogue2
// ---------------------------------------------------------------------------
__global__ __launch_bounds__(256) void aggregate2(
    const int* __restrict__ rowptr,
    const int* __restrict__ col,
    const float* __restrict__ h3s,
    const float* __restrict__ dinv,
    const float* __restrict__ b2,
    float* __restrict__ out) {
    int node = blockIdx.x * 8 + (threadIdx.x >> 5);
    int c    = threadIdx.x & 31;
    if (node >= N_NODES) return;

    int e0 = rowptr[node];
    int e1 = rowptr[node + 1];
    float a0 = h3s[(size_t)node * HID + c];  // self-loop
    float a1 = 0.f, a2 = 0.f, a3 = 0.f;
    int e = e0;
    for (; e + 4 <= e1; e += 4) {
        int s0 = col[e], s1 = col[e + 1], s2 = col[e + 2], s3 = col[e + 3];
        a0 += h3s[(size_t)s0 * HID + c];
        a1 += h3s[(size_t)s1 * HID + c];
        a2 += h3s[(size_t)s2 * HID + c];
        a3 += h3s[(size_t)s3 * HID + c];
    }
    for (; e < e1; ++e)
        a1 += h3s[(size_t)col[e] * HID + c];

    out[(size_t)node * HID + c] = ((a0 + a1) + (a2 + a3)) * dinv[node] + b2[c];
}

// ---------------------------------------------------------------------------
extern "C" void kernel_launch(void* const* d_in, const int* in_sizes, int n_in,
                              void* d_out, int out_size, void* d_ws, size_t ws_size,
                              hipStream_t stream) {
    const float* x  = (const float*)d_in[0];
    const int*   ei = (const int*)d_in[1];
    const float* W1 = (const float*)d_in[2];
    const float* b1 = (const float*)d_in[3];
    const float* W2 = (const float*)d_in[4];
    const float* b2 = (const float*)d_in[5];
    float* out = (float*)d_out;

    // workspace: flag[64] | deg[N] | rowptr[N+1] | partials[128] | bcur[512] |
    //            ebuf[E] | col[E] | dinv[N] | h1s[N*32] | h3s[N*32]  (~53 MiB)
    int*          flag     = (int*)d_ws;
    int*          deg      = flag + 64;
    int*          rowptr   = deg + N_NODES;
    int*          partials = rowptr + (N_NODES + 1);
    int*          bcur     = partials + 128;
    unsigned int* ebuf     = (unsigned int*)(bcur + NB);
    int*          col      = (int*)(ebuf + N_EDGES);
    float*        dinv     = (float*)(col + N_EDGES);
    float*        h1s      = dinv + N_NODES;
    float*        h3s      = h1s + (size_t)N_NODES * HID;

    const int nodeBlocks  = (N_NODES + 255) / 256;   // 391
    const int node1Blocks = (N_NODES + 256) / 256;   // 392 (covers i==N)
    const int gemmBlocks  = (N_NODES + 7) / 8;       // 12500
    const int edgeBlocks  = (N_EDGES + 255) / 256;   // 12500
    const int scanBlocks  = (N_NODES + 1023) / 1024; // 98

    detect_idx<<<1, 256, 0, stream>>>(ei, flag);

    // degrees + rowptr
    zero_deg<<<nodeBlocks, 256, 0, stream>>>(deg);
    count_deg<<<edgeBlocks, 256, 0, stream>>>(ei, flag, deg);
    make_dinv<<<nodeBlocks, 256, 0, stream>>>(deg, dinv);
    scan_s1<<<scanBlocks, 256, 0, stream>>>(deg, rowptr, partials);
    scan_s2<<<1, 128, 0, stream>>>(partials);
    scan_s3<<<node1Blocks, 256, 0, stream>>>(rowptr, partials);

    // bucketed CSR build
    bcur_init<<<(NB + 255) / 256, 256, 0, stream>>>(rowptr, bcur);
    bucket_scatter<<<edgeBlocks, 256, 0, stream>>>(ei, flag, bcur, ebuf);
    fill_csr2<<<NB, 256, 0, stream>>>(rowptr, ebuf, col);

    // layer 1 (+ fused relu + gemm2)
    gemm1_scale<<<gemmBlocks, 256, 0, stream>>>(x, W1, dinv, h1s);
    aggregate1<<<gemmBlocks, 256, 0, stream>>>(rowptr, col, h1s, dinv, b1, W2, h3s);

    // layer 2 (+ fused epilogue)
    aggregate2<<<gemmBlocks, 256, 0, stream>>>(rowptr, col, h3s, dinv, b2, out);
}

// Round 5
// 549.018 us; speedup vs baseline: 2.6683x; 2.6683x over previous
//
#include <hip/hip_runtime.h>
#include <hip/hip_bf16.h>

#define N_NODES 100000
#define N_EDGES 3200000
#define IN_CH   128
#define HID     32
#define NB      512              // dst buckets for CSR build
#define NPB     196              // nodes per bucket (512*196 >= 100000)
#define MAXBE   8192             // LDS staging capacity per bucket (edges)
#define CHUNK   8192             // edges per block in bucket_scatter2

// ---------------------------------------------------------------------------
// Detect whether edge_index is int64 (odd 32-bit words all zero) or int32.
// ---------------------------------------------------------------------------
__global__ __launch_bounds__(256) void detect_idx(const int* __restrict__ ei,
                                                  int* __restrict__ flag) {
    __shared__ int nz;
    if (threadIdx.x == 0) nz = 0;
    __syncthreads();
    if (ei[2 * threadIdx.x + 1] != 0) atomicAdd(&nz, 1);
    __syncthreads();
    if (threadIdx.x == 0) flag[0] = (nz == 0) ? 1 : 0;
}

__device__ __forceinline__ int edge_at(const int* __restrict__ ei, int idx64,
                                       size_t pos) {
    if (idx64) return (int)((const long long*)ei)[pos];
    return ei[pos];
}

// ---------------------------------------------------------------------------
// Degree / normalization
// ---------------------------------------------------------------------------
__global__ __launch_bounds__(256) void zero_deg(int* __restrict__ deg) {
    int i = blockIdx.x * 256 + threadIdx.x;
    if (i < N_NODES) deg[i] = 0;
}

__global__ __launch_bounds__(256) void count_deg(const int* __restrict__ ei,
                                                 const int* __restrict__ flag,
                                                 int* __restrict__ deg) {
    int i = blockIdx.x * 256 + threadIdx.x;
    if (i >= N_EDGES) return;
    int idx64 = flag[0];
    int d = edge_at(ei, idx64, (size_t)N_EDGES + i);   // dst = edge_index[1]
    atomicAdd(&deg[d], 1);
}

__global__ __launch_bounds__(256) void make_dinv(const int* __restrict__ deg,
                                                 float* __restrict__ dinv) {
    int i = blockIdx.x * 256 + threadIdx.x;
    if (i < N_NODES) dinv[i] = rsqrtf((float)(deg[i] + 1));  // +1 self-loop
}

// --- exclusive scan of deg -> rowptr (3 kernels) ---------------------------
__global__ __launch_bounds__(256) void scan_s1(const int* __restrict__ deg,
                                               int* __restrict__ rowptr,
                                               int* __restrict__ partials) {
    __shared__ int tmp[256];
    int t = threadIdx.x;
    int base = blockIdx.x * 1024;
    int v[4];
#pragma unroll
    for (int j = 0; j < 4; ++j) {
        int idx = base + t * 4 + j;
        v[j] = (idx < N_NODES) ? deg[idx] : 0;
    }
    int s = v[0] + v[1] + v[2] + v[3];
    tmp[t] = s;
    __syncthreads();
    for (int off = 1; off < 256; off <<= 1) {
        int x = 0;
        if (t >= off) x = tmp[t - off];
        __syncthreads();
        if (t >= off) tmp[t] += x;
        __syncthreads();
    }
    int run = tmp[t] - s;
#pragma unroll
    for (int j = 0; j < 4; ++j) {
        int idx = base + t * 4 + j;
        if (idx < N_NODES) rowptr[idx] = run;
        run += v[j];
    }
    if (t == 255) partials[blockIdx.x] = tmp[255];
}

__global__ __launch_bounds__(128) void scan_s2(int* __restrict__ partials) {
    __shared__ int tmp[128];
    int t = threadIdx.x;
    int v = (t < 98) ? partials[t] : 0;
    tmp[t] = v;
    __syncthreads();
    for (int off = 1; off < 128; off <<= 1) {
        int x = 0;
        if (t >= off) x = tmp[t - off];
        __syncthreads();
        if (t >= off) tmp[t] += x;
        __syncthreads();
    }
    if (t < 98) partials[t] = tmp[t] - v;
}

__global__ __launch_bounds__(256) void scan_s3(int* __restrict__ rowptr,
                                               const int* __restrict__ partials) {
    int i = blockIdx.x * 256 + threadIdx.x;
    if (i < N_NODES) rowptr[i] += partials[i >> 10];
    if (i == N_NODES) rowptr[N_NODES] = N_EDGES;
}

// ---------------------------------------------------------------------------
// Bucket pass: bucket b = contiguous node range [b*NPB, (b+1)*NPB), so
// bucket base offsets come straight from rowptr — no extra histogram.
// ---------------------------------------------------------------------------
__global__ __launch_bounds__(256) void bcur_init(const int* __restrict__ rowptr,
                                                 int* __restrict__ bcur) {
    int b = blockIdx.x * 256 + threadIdx.x;
    if (b < NB) {
        int n0 = b * NPB;
        if (n0 > N_NODES) n0 = N_NODES;
        bcur[b] = rowptr[n0];
    }
}

// Scatter edges into dst-bucket-partitioned ebuf, 4 B packed (s<<8)|dloc.
// Block-level pre-aggregation: stage CHUNK edges in LDS, LDS histogram,
// ONE global atomicAdd per (block, nonzero-bucket) to reserve a contiguous
// range, then scatter from LDS. Avoids the 6250-deep serial atomic chains
// that made the naive per-edge version run at 953 us.
__global__ __launch_bounds__(256) void bucket_scatter2(
    const int* __restrict__ ei,
    const int* __restrict__ flag,
    int* __restrict__ bcur,
    unsigned int* __restrict__ ebuf) {
    __shared__ unsigned int   pk[CHUNK];     // 32 KB  packed (s<<8)|dloc
    __shared__ unsigned short bb[CHUNK];     // 16 KB  bucket id per edge
    __shared__ int cnt[NB];                  // 2 KB   block histogram
    __shared__ int cnt2[NB];                 // 2 KB   scatter cursor
    __shared__ int base_l[NB];               // 2 KB   reserved global base

    int t = threadIdx.x;
    for (int j = t; j < NB; j += 256) { cnt[j] = 0; cnt2[j] = 0; }
    __syncthreads();

    int e0 = blockIdx.x * CHUNK;
    int nE = N_EDGES - e0; if (nE > CHUNK) nE = CHUNK;
    int idx64 = flag[0];

    for (int i = t; i < nE; i += 256) {
        unsigned int s = (unsigned int)edge_at(ei, idx64, (size_t)(e0 + i));
        unsigned int d = (unsigned int)edge_at(ei, idx64, (size_t)N_EDGES + e0 + i);
        unsigned int b = d / NPB;            // compile-time const -> magic mul
        pk[i] = (s << 8) | (d - b * NPB);
        bb[i] = (unsigned short)b;
        atomicAdd(&cnt[b], 1);               // LDS atomic
    }
    __syncthreads();

    for (int j = t; j < NB; j += 256) {
        int c = cnt[j];
        if (c > 0) base_l[j] = atomicAdd(&bcur[j], c);   // one per bucket
    }
    __syncthreads();

    for (int i = t; i < nE; i += 256) {
        int b = bb[i];
        int p = atomicAdd(&cnt2[b], 1);      // LDS atomic
        ebuf[base_l[b] + p] = pk[i];
    }
}

// per-bucket CSR fill: scatter inside LDS, copy out coalesced. (~19 us)
__global__ __launch_bounds__(256) void fill_csr2(
    const int* __restrict__ rowptr,
    const unsigned int* __restrict__ ebuf,
    int* __restrict__ col) {
    __shared__ int lcur[NPB];
    __shared__ int lbuf[MAXBE];
    int b = blockIdx.x;
    int n0 = b * NPB;        if (n0 > N_NODES) n0 = N_NODES;
    int n1 = n0 + NPB;       if (n1 > N_NODES) n1 = N_NODES;
    int E0 = rowptr[n0];
    int E1 = rowptr[n1];
    int nn = n1 - n0;
    for (int j = threadIdx.x; j < nn; j += 256)
        lcur[j] = rowptr[n0 + j] - E0;
    __syncthreads();
    int sz = E1 - E0;
    if (sz <= MAXBE) {
        for (int i = E0 + threadIdx.x; i < E1; i += 256) {
            unsigned int e = ebuf[i];
            int p = atomicAdd(&lcur[e & 255u], 1);
            lbuf[p] = (int)(e >> 8);
        }
        __syncthreads();
        for (int j = threadIdx.x; j < sz; j += 256)
            col[E0 + j] = lbuf[j];
    } else {  // overflow fallback (statistically unreachable for uniform dst)
        for (int i = E0 + threadIdx.x; i < E1; i += 256) {
            unsigned int e = ebuf[i];
            int p = atomicAdd(&lcur[e & 255u], 1);
            col[E0 + p] = (int)(e >> 8);
        }
    }
}

// ---------------------------------------------------------------------------
// GEMM1: h1s[n][c] = (sum_k x[n][k] * W1[k][c]) * dinv[n]
// ---------------------------------------------------------------------------
__global__ __launch_bounds__(256) void gemm1_scale(
    const float* __restrict__ x,
    const float* __restrict__ W1,
    const float* __restrict__ dinv,
    float* __restrict__ h1s) {
    __shared__ float w[IN_CH * HID];   // 16 KB
    for (int i = threadIdx.x; i < IN_CH * HID; i += 256)
        w[i] = W1[i];
    __syncthreads();

    int node = blockIdx.x * 8 + (threadIdx.x >> 5);
    int c    = threadIdx.x & 31;
    if (node >= N_NODES) return;

    const float4* xr = reinterpret_cast<const float4*>(x + (size_t)node * IN_CH);
    float acc = 0.0f;
#pragma unroll
    for (int k4 = 0; k4 < IN_CH / 4; ++k4) {
        float4 v = xr[k4];
        acc += v.x * w[(k4 * 4 + 0) * HID + c]
             + v.y * w[(k4 * 4 + 1) * HID + c]
             + v.z * w[(k4 * 4 + 2) * HID + c]
             + v.w * w[(k4 * 4 + 3) * HID + c];
    }
    h1s[(size_t)node * HID + c] = acc * dinv[node];
}

// ---------------------------------------------------------------------------
// Layer-1 aggregate, fused: gather-sum + relu + gemm2 (lane shuffles) -> h3s
// ---------------------------------------------------------------------------
__global__ __launch_bounds__(256) void aggregate1(
    const int* __restrict__ rowptr,
    const int* __restrict__ col,
    const float* __restrict__ h1s,
    const float* __restrict__ dinv,
    const float* __restrict__ b1,
    const float* __restrict__ W2,
    float* __restrict__ h3s) {
    __shared__ float w2s[HID * HID];   // 4 KB
    for (int i = threadIdx.x; i < HID * HID; i += 256)
        w2s[i] = W2[i];
    __syncthreads();

    int node = blockIdx.x * 8 + (threadIdx.x >> 5);
    int c    = threadIdx.x & 31;
    if (node >= N_NODES) return;

    int e0 = rowptr[node];
    int e1 = rowptr[node + 1];
    float a0 = h1s[(size_t)node * HID + c];  // self-loop
    float a1 = 0.f, a2 = 0.f, a3 = 0.f;
    int e = e0;
    for (; e + 4 <= e1; e += 4) {
        int s0 = col[e], s1 = col[e + 1], s2 = col[e + 2], s3 = col[e + 3];
        a0 += h1s[(size_t)s0 * HID + c];
        a1 += h1s[(size_t)s1 * HID + c];
        a2 += h1s[(size_t)s2 * HID + c];
        a3 += h1s[(size_t)s3 * HID + c];
    }
    for (; e < e1; ++e)
        a1 += h1s[(size_t)col[e] * HID + c];

    float dn = dinv[node];
    float h2v = ((a0 + a1) + (a2 + a3)) * dn + b1[c];
    h2v = h2v > 0.0f ? h2v : 0.0f;

    float acc2 = 0.0f;
#pragma unroll
    for (int k = 0; k < HID; ++k)
        acc2 += __shfl(h2v, k, 32) * w2s[k * HID + c];

    h3s[(size_t)node * HID + c] = acc2 * dn;
}

// ---------------------------------------------------------------------------
// Layer-2 aggregate, fused epilogue2
// ---------------------------------------------------------------------------
__global__ __launch_bounds__(256) void aggregate2(
    const int* __restrict__ rowptr,
    const int* __restrict__ col,
    const float* __restrict__ h3s,
    const float* __restrict__ dinv,
    const float* __restrict__ b2,
    float* __restrict__ out) {
    int node = blockIdx.x * 8 + (threadIdx.x >> 5);
    int c    = threadIdx.x & 31;
    if (node >= N_NODES) return;

    int e0 = rowptr[node];
    int e1 = rowptr[node + 1];
    float a0 = h3s[(size_t)node * HID + c];  // self-loop
    float a1 = 0.f, a2 = 0.f, a3 = 0.f;
    int e = e0;
    for (; e + 4 <= e1; e += 4) {
        int s0 = col[e], s1 = col[e + 1], s2 = col[e + 2], s3 = col[e + 3];
        a0 += h3s[(size_t)s0 * HID + c];
        a1 += h3s[(size_t)s1 * HID + c];
        a2 += h3s[(size_t)s2 * HID + c];
        a3 += h3s[(size_t)s3 * HID + c];
    }
    for (; e < e1; ++e)
        a1 += h3s[(size_t)col[e] * HID + c];

    out[(size_t)node * HID + c] = ((a0 + a1) + (a2 + a3)) * dinv[node] + b2[c];
}

// ---------------------------------------------------------------------------
extern "C" void kernel_launch(void* const* d_in, const int* in_sizes, int n_in,
                              void* d_out, int out_size, void* d_ws, size_t ws_size,
                              hipStream_t stream) {
    const float* x  = (const float*)d_in[0];
    const int*   ei = (const int*)d_in[1];
    const float* W1 = (const float*)d_in[2];
    const float* b1 = (const float*)d_in[3];
    const float* W2 = (const float*)d_in[4];
    const float* b2 = (const float*)d_in[5];
    float* out = (float*)d_out;

    // workspace: flag[64] | deg[N] | rowptr[N+1] | partials[128] | bcur[512] |
    //            ebuf[E] | col[E] | dinv[N] | h1s[N*32] | h3s[N*32]  (~53 MiB)
    int*          flag     = (int*)d_ws;
    int*          deg      = flag + 64;
    int*          rowptr   = deg + N_NODES;
    int*          partials = rowptr + (N_NODES + 1);
    int*          bcur     = partials + 128;
    unsigned int* ebuf     = (unsigned int*)(bcur + NB);
    int*          col      = (int*)(ebuf + N_EDGES);
    float*        dinv     = (float*)(col + N_EDGES);
    float*        h1s      = dinv + N_NODES;
    float*        h3s      = h1s + (size_t)N_NODES * HID;

    const int nodeBlocks  = (N_NODES + 255) / 256;      // 391
    const int node1Blocks = (N_NODES + 256) / 256;      // 392 (covers i==N)
    const int gemmBlocks  = (N_NODES + 7) / 8;          // 12500
    const int edgeBlocks  = (N_EDGES + 255) / 256;      // 12500
    const int scanBlocks  = (N_NODES + 1023) / 1024;    // 98
    const int chunkBlocks = (N_EDGES + CHUNK - 1) / CHUNK;  // 391

    detect_idx<<<1, 256, 0, stream>>>(ei, flag);

    // degrees + rowptr
    zero_deg<<<nodeBlocks, 256, 0, stream>>>(deg);
    count_deg<<<edgeBlocks, 256, 0, stream>>>(ei, flag, deg);
    make_dinv<<<nodeBlocks, 256, 0, stream>>>(deg, dinv);
    scan_s1<<<scanBlocks, 256, 0, stream>>>(deg, rowptr, partials);
    scan_s2<<<1, 128, 0, stream>>>(partials);
    scan_s3<<<node1Blocks, 256, 0, stream>>>(rowptr, partials);

    // bucketed CSR build
    bcur_init<<<(NB + 255) / 256, 256, 0, stream>>>(rowptr, bcur);
    bucket_scatter2<<<chunkBlocks, 256, 0, stream>>>(ei, flag, bcur, ebuf);
    fill_csr2<<<NB, 256, 0, stream>>>(rowptr, ebuf, col);

    // layer 1 (+ fused relu + gemm2)
    gemm1_scale<<<gemmBlocks, 256, 0, stream>>>(x, W1, dinv, h1s);
    aggregate1<<<gemmBlocks, 256, 0, stream>>>(rowptr, col, h1s, dinv, b1, W2, h3s);

    // layer 2 (+ fused epilogue)
    aggregate2<<<gemmBlocks, 256, 0, stream>>>(rowptr, col, h3s, dinv, b2, out);
}

// Round 6
// 414.648 us; speedup vs baseline: 3.5330x; 1.3241x over previous
//
#include <hip/hip_runtime.h>
#include <hip/hip_bf16.h>

#define N_NODES 100000
#define N_EDGES 3200000
#define IN_CH   128
#define HID     32
#define NB      512              // dst buckets for CSR build
#define NPB     196              // nodes per bucket (512*196 >= 100000)
#define CAP     8192             // fixed per-bucket region capacity (mean 6250, 24 sigma)
#define CHUNK   8192             // edges per block in bucket_scatter2

// ---------------------------------------------------------------------------
// Detect whether edge_index is int64 (odd 32-bit words all zero) or int32.
// ---------------------------------------------------------------------------
__global__ __launch_bounds__(256) void detect_idx(const int* __restrict__ ei,
                                                  int* __restrict__ flag) {
    __shared__ int nz;
    if (threadIdx.x == 0) nz = 0;
    __syncthreads();
    if (ei[2 * threadIdx.x + 1] != 0) atomicAdd(&nz, 1);
    __syncthreads();
    if (threadIdx.x == 0) flag[0] = (nz == 0) ? 1 : 0;
}

__device__ __forceinline__ int edge_at(const int* __restrict__ ei, int idx64,
                                       size_t pos) {
    if (idx64) return (int)((const long long*)ei)[pos];
    return ei[pos];
}

__global__ __launch_bounds__(256) void bcur_init(int* __restrict__ bcur) {
    int b = blockIdx.x * 256 + threadIdx.x;
    if (b < NB) bcur[b] = b * CAP;
}

// ---------------------------------------------------------------------------
// Scatter edges into fixed-capacity dst-bucket regions of ebuf, 4 B packed
// (s<<8)|dloc. Block-level pre-aggregation: stage CHUNK edges in LDS, LDS
// histogram, ONE global atomicAdd per (block, nonzero-bucket), scatter from
// LDS. (Per-edge global atomics on 512 cursors serialized at 953 us; this
// runs the same work in ~tens of us.)
// ---------------------------------------------------------------------------
__global__ __launch_bounds__(256) void bucket_scatter2(
    const int* __restrict__ ei,
    const int* __restrict__ flag,
    int* __restrict__ bcur,
    unsigned int* __restrict__ ebuf) {
    __shared__ unsigned int   pk[CHUNK];     // 32 KB  packed (s<<8)|dloc
    __shared__ unsigned short bb[CHUNK];     // 16 KB  bucket id per edge
    __shared__ int cnt[NB];                  // 2 KB   block histogram
    __shared__ int cnt2[NB];                 // 2 KB   scatter cursor
    __shared__ int base_l[NB];               // 2 KB   reserved global base

    int t = threadIdx.x;
    for (int j = t; j < NB; j += 256) { cnt[j] = 0; cnt2[j] = 0; }
    __syncthreads();

    int e0 = blockIdx.x * CHUNK;
    int nE = N_EDGES - e0; if (nE > CHUNK) nE = CHUNK;
    int idx64 = flag[0];

    for (int i = t; i < nE; i += 256) {
        unsigned int s = (unsigned int)edge_at(ei, idx64, (size_t)(e0 + i));
        unsigned int d = (unsigned int)edge_at(ei, idx64, (size_t)N_EDGES + e0 + i);
        unsigned int b = d / NPB;            // compile-time const -> magic mul
        pk[i] = (s << 8) | (d - b * NPB);
        bb[i] = (unsigned short)b;
        atomicAdd(&cnt[b], 1);               // LDS atomic
    }
    __syncthreads();

    for (int j = t; j < NB; j += 256) {
        int c = cnt[j];
        if (c > 0) base_l[j] = atomicAdd(&bcur[j], c);   // one per bucket
    }
    __syncthreads();

    for (int i = t; i < nE; i += 256) {
        int b = bb[i];
        int p = atomicAdd(&cnt2[b], 1);      // LDS atomic
        ebuf[base_l[b] + p] = pk[i];
    }
}

// ---------------------------------------------------------------------------
// Exclusive scan of the 512 final bucket counts -> gbase (single block).
// ---------------------------------------------------------------------------
__global__ __launch_bounds__(512) void scan_buckets(const int* __restrict__ bcur,
                                                    int* __restrict__ gbase,
                                                    int* __restrict__ rowptr) {
    __shared__ int tmp[512];
    int t = threadIdx.x;
    int c = bcur[t] - t * CAP;               // this bucket's edge count
    tmp[t] = c;
    __syncthreads();
    for (int off = 1; off < 512; off <<= 1) {
        int x = 0;
        if (t >= off) x = tmp[t - off];
        __syncthreads();
        if (t >= off) tmp[t] += x;
        __syncthreads();
    }
    gbase[t] = tmp[t] - c;                   // exclusive
    if (t == 511) rowptr[N_NODES] = N_EDGES;
}

// ---------------------------------------------------------------------------
// Per-bucket finalize: bucket-local dst histogram (= per-node degree) -> dinv,
// local exclusive scan -> rowptr, LDS scatter -> coalesced col.
// Replaces count_deg (128 us of atomic write-through) + scan_s1/s2/s3 +
// make_dinv + fill_csr2.
// ---------------------------------------------------------------------------
__global__ __launch_bounds__(256) void fill_csr3(
    const int* __restrict__ bcur,
    const int* __restrict__ gbase,
    const unsigned int* __restrict__ ebuf,
    int* __restrict__ rowptr,
    float* __restrict__ dinv,
    int* __restrict__ col) {
    __shared__ int lhist[NPB];
    __shared__ int lrow[NPB];      // exclusive offsets, then scatter cursors
    __shared__ int tmp[256];
    __shared__ int lbuf[CAP];      // 32 KB
    int b = blockIdx.x;
    int t = threadIdx.x;
    int n0 = b * NPB;  if (n0 > N_NODES) n0 = N_NODES;
    int n1 = n0 + NPB; if (n1 > N_NODES) n1 = N_NODES;
    int nn  = n1 - n0;
    int cnt = bcur[b] - b * CAP;
    int E0  = gbase[b];
    const unsigned int* reg = ebuf + (size_t)b * CAP;

    for (int j = t; j < NPB; j += 256) lhist[j] = 0;
    __syncthreads();
    for (int i = t; i < cnt; i += 256)
        atomicAdd(&lhist[reg[i] & 255u], 1);     // LDS histogram
    __syncthreads();

    // fused make_dinv (self-loop +1)
    for (int j = t; j < nn; j += 256)
        dinv[n0 + j] = rsqrtf((float)(lhist[j] + 1));

    // exclusive scan of lhist[0..nn) (NPB < 256: one Hillis-Steele pass)
    int v = (t < NPB) ? lhist[t] : 0;
    tmp[t] = v;
    __syncthreads();
    for (int off = 1; off < 256; off <<= 1) {
        int x = 0;
        if (t >= off) x = tmp[t - off];
        __syncthreads();
        if (t >= off) tmp[t] += x;
        __syncthreads();
    }
    if (t < NPB) lrow[t] = tmp[t] - v;
    __syncthreads();

    for (int j = t; j < nn; j += 256)
        rowptr[n0 + j] = E0 + lrow[j];
    __syncthreads();               // rowptr reads lrow before cursor mutation

    for (int i = t; i < cnt; i += 256) {
        unsigned int e = reg[i];
        int p = atomicAdd(&lrow[e & 255u], 1);
        lbuf[p] = (int)(e >> 8);
    }
    __syncthreads();
    for (int j = t; j < cnt; j += 256)
        col[E0 + j] = lbuf[j];
}

// ---------------------------------------------------------------------------
// GEMM1: h1s[n][c] = (sum_k x[n][k] * W1[k][c]) * dinv[n]
// ---------------------------------------------------------------------------
__global__ __launch_bounds__(256) void gemm1_scale(
    const float* __restrict__ x,
    const float* __restrict__ W1,
    const float* __restrict__ dinv,
    float* __restrict__ h1s) {
    __shared__ float w[IN_CH * HID];   // 16 KB
    for (int i = threadIdx.x; i < IN_CH * HID; i += 256)
        w[i] = W1[i];
    __syncthreads();

    int node = blockIdx.x * 8 + (threadIdx.x >> 5);
    int c    = threadIdx.x & 31;
    if (node >= N_NODES) return;

    const float4* xr = reinterpret_cast<const float4*>(x + (size_t)node * IN_CH);
    float acc = 0.0f;
#pragma unroll
    for (int k4 = 0; k4 < IN_CH / 4; ++k4) {
        float4 v = xr[k4];
        acc += v.x * w[(k4 * 4 + 0) * HID + c]
             + v.y * w[(k4 * 4 + 1) * HID + c]
             + v.z * w[(k4 * 4 + 2) * HID + c]
             + v.w * w[(k4 * 4 + 3) * HID + c];
    }
    h1s[(size_t)node * HID + c] = acc * dinv[node];
}

// ---------------------------------------------------------------------------
// Layer-1 aggregate, fused: gather-sum + relu + gemm2 (lane shuffles) -> h3s
// ---------------------------------------------------------------------------
__global__ __launch_bounds__(256) void aggregate1(
    const int* __restrict__ rowptr,
    const int* __restrict__ col,
    const float* __restrict__ h1s,
    const float* __restrict__ dinv,
    const float* __restrict__ b1,
    const float* __restrict__ W2,
    float* __restrict__ h3s) {
    __shared__ float w2s[HID * HID];   // 4 KB
    for (int i = threadIdx.x; i < HID * HID; i += 256)
        w2s[i] = W2[i];
    __syncthreads();

    int node = blockIdx.x * 8 + (threadIdx.x >> 5);
    int c    = threadIdx.x & 31;
    if (node >= N_NODES) return;

    int e0 = rowptr[node];
    int e1 = rowptr[node + 1];
    float a0 = h1s[(size_t)node * HID + c];  // self-loop
    float a1 = 0.f, a2 = 0.f, a3 = 0.f;
    int e = e0;
    for (; e + 4 <= e1; e += 4) {
        int s0 = col[e], s1 = col[e + 1], s2 = col[e + 2], s3 = col[e + 3];
        a0 += h1s[(size_t)s0 * HID + c];
        a1 += h1s[(size_t)s1 * HID + c];
        a2 += h1s[(size_t)s2 * HID + c];
        a3 += h1s[(size_t)s3 * HID + c];
    }
    for (; e < e1; ++e)
        a1 += h1s[(size_t)col[e] * HID + c];

    float dn = dinv[node];
    float h2v = ((a0 + a1) + (a2 + a3)) * dn + b1[c];
    h2v = h2v > 0.0f ? h2v : 0.0f;

    float acc2 = 0.0f;
#pragma unroll
    for (int k = 0; k < HID; ++k)
        acc2 += __shfl(h2v, k, 32) * w2s[k * HID + c];

    h3s[(size_t)node * HID + c] = acc2 * dn;
}

// ---------------------------------------------------------------------------
// Layer-2 aggregate, fused epilogue2
// ---------------------------------------------------------------------------
__global__ __launch_bounds__(256) void aggregate2(
    const int* __restrict__ rowptr,
    const int* __restrict__ col,
    const float* __restrict__ h3s,
    const float* __restrict__ dinv,
    const float* __restrict__ b2,
    float* __restrict__ out) {
    int node = blockIdx.x * 8 + (threadIdx.x >> 5);
    int c    = threadIdx.x & 31;
    if (node >= N_NODES) return;

    int e0 = rowptr[node];
    int e1 = rowptr[node + 1];
    float a0 = h3s[(size_t)node * HID + c];  // self-loop
    float a1 = 0.f, a2 = 0.f, a3 = 0.f;
    int e = e0;
    for (; e + 4 <= e1; e += 4) {
        int s0 = col[e], s1 = col[e + 1], s2 = col[e + 2], s3 = col[e + 3];
        a0 += h3s[(size_t)s0 * HID + c];
        a1 += h3s[(size_t)s1 * HID + c];
        a2 += h3s[(size_t)s2 * HID + c];
        a3 += h3s[(size_t)s3 * HID + c];
    }
    for (; e < e1; ++e)
        a1 += h3s[(size_t)col[e] * HID + c];

    out[(size_t)node * HID + c] = ((a0 + a1) + (a2 + a3)) * dinv[node] + b2[c];
}

// ---------------------------------------------------------------------------
extern "C" void kernel_launch(void* const* d_in, const int* in_sizes, int n_in,
                              void* d_out, int out_size, void* d_ws, size_t ws_size,
                              hipStream_t stream) {
    const float* x  = (const float*)d_in[0];
    const int*   ei = (const int*)d_in[1];
    const float* W1 = (const float*)d_in[2];
    const float* b1 = (const float*)d_in[3];
    const float* W2 = (const float*)d_in[4];
    const float* b2 = (const float*)d_in[5];
    float* out = (float*)d_out;

    // workspace: flag[64] | bcur[512] | gbase[512] | rowptr[N+1] | col[E] |
    //            dinv[N] | h1s[N*32] | h3s[N*32]
    // ebuf (512*CAP u32 = 16 MB) ALIASES h1s/h3s (25.6 MB): ebuf is dead
    // before gemm1 writes h1s. Total ~39 MiB.
    int*          flag   = (int*)d_ws;
    int*          bcur   = flag + 64;
    int*          gbase  = bcur + NB;
    int*          rowptr = gbase + NB;
    int*          col    = rowptr + (N_NODES + 1);
    float*        dinv   = (float*)(col + N_EDGES);
    float*        h1s    = dinv + N_NODES;
    float*        h3s    = h1s + (size_t)N_NODES * HID;
    unsigned int* ebuf   = (unsigned int*)h1s;           // alias, dead by gemm1

    const int gemmBlocks  = (N_NODES + 7) / 8;               // 12500
    const int chunkBlocks = (N_EDGES + CHUNK - 1) / CHUNK;   // 391

    detect_idx<<<1, 256, 0, stream>>>(ei, flag);

    // bucketed CSR build (single pass over edge_index)
    bcur_init<<<(NB + 255) / 256, 256, 0, stream>>>(bcur);
    bucket_scatter2<<<chunkBlocks, 256, 0, stream>>>(ei, flag, bcur, ebuf);
    scan_buckets<<<1, 512, 0, stream>>>(bcur, gbase, rowptr);
    fill_csr3<<<NB, 256, 0, stream>>>(bcur, gbase, ebuf, rowptr, dinv, col);

    // layer 1 (+ fused relu + gemm2)
    gemm1_scale<<<gemmBlocks, 256, 0, stream>>>(x, W1, dinv, h1s);
    aggregate1<<<gemmBlocks, 256, 0, stream>>>(rowptr, col, h1s, dinv, b1, W2, h3s);

    // layer 2 (+ fused epilogue)
    aggregate2<<<gemmBlocks, 256, 0, stream>>>(rowptr, col, h3s, dinv, b2, out);
}

// Round 7
// 365.894 us; speedup vs baseline: 4.0037x; 1.1332x over previous
//
#include <hip/hip_runtime.h>
#include <hip/hip_bf16.h>

#define N_NODES 100000
#define N_EDGES 3200000
#define IN_CH   128
#define HID     32
#define NB      512              // dst buckets for CSR build
#define NPB     196              // nodes per bucket (512*196 >= 100000)
#define CAP     8192             // fixed per-bucket region capacity (mean 6250, 24 sigma)
#define CHUNK   8192             // edges per block in bucket_scatter2

// --- bf16x2 pack/unpack (round-to-nearest-even) ----------------------------
__device__ __forceinline__ unsigned int pack_bf16x2(float a, float b) {
    unsigned int ua = __float_as_uint(a);
    unsigned int ub = __float_as_uint(b);
    ua = (ua + 0x7FFFu + ((ua >> 16) & 1u)) >> 16;
    ub = (ub + 0x7FFFu + ((ub >> 16) & 1u)) >> 16;
    return (ua & 0xFFFFu) | (ub << 16);
}
__device__ __forceinline__ float bf_lo(unsigned int v) { return __uint_as_float(v << 16); }
__device__ __forceinline__ float bf_hi(unsigned int v) { return __uint_as_float(v & 0xFFFF0000u); }

// ---------------------------------------------------------------------------
// Detect whether edge_index is int64 (odd 32-bit words all zero) or int32.
// ---------------------------------------------------------------------------
__global__ __launch_bounds__(256) void detect_idx(const int* __restrict__ ei,
                                                  int* __restrict__ flag) {
    __shared__ int nz;
    if (threadIdx.x == 0) nz = 0;
    __syncthreads();
    if (ei[2 * threadIdx.x + 1] != 0) atomicAdd(&nz, 1);
    __syncthreads();
    if (threadIdx.x == 0) flag[0] = (nz == 0) ? 1 : 0;
}

__device__ __forceinline__ int edge_at(const int* __restrict__ ei, int idx64,
                                       size_t pos) {
    if (idx64) return (int)((const long long*)ei)[pos];
    return ei[pos];
}

__global__ __launch_bounds__(256) void bcur_init(int* __restrict__ bcur) {
    int b = blockIdx.x * 256 + threadIdx.x;
    if (b < NB) bcur[b] = b * CAP;
}

// ---------------------------------------------------------------------------
// Scatter edges into fixed-capacity dst-bucket regions of ebuf, 4 B packed
// (s<<8)|dloc. Block-level pre-aggregation keeps global atomics to one per
// (block, nonzero-bucket).
// ---------------------------------------------------------------------------
__global__ __launch_bounds__(256) void bucket_scatter2(
    const int* __restrict__ ei,
    const int* __restrict__ flag,
    int* __restrict__ bcur,
    unsigned int* __restrict__ ebuf) {
    __shared__ unsigned int   pk[CHUNK];     // 32 KB  packed (s<<8)|dloc
    __shared__ unsigned short bb[CHUNK];     // 16 KB  bucket id per edge
    __shared__ int cnt[NB];                  // 2 KB   block histogram
    __shared__ int cnt2[NB];                 // 2 KB   scatter cursor
    __shared__ int base_l[NB];               // 2 KB   reserved global base

    int t = threadIdx.x;
    for (int j = t; j < NB; j += 256) { cnt[j] = 0; cnt2[j] = 0; }
    __syncthreads();

    int e0 = blockIdx.x * CHUNK;
    int nE = N_EDGES - e0; if (nE > CHUNK) nE = CHUNK;
    int idx64 = flag[0];

    for (int i = t; i < nE; i += 256) {
        unsigned int s = (unsigned int)edge_at(ei, idx64, (size_t)(e0 + i));
        unsigned int d = (unsigned int)edge_at(ei, idx64, (size_t)N_EDGES + e0 + i);
        unsigned int b = d / NPB;            // compile-time const -> magic mul
        pk[i] = (s << 8) | (d - b * NPB);
        bb[i] = (unsigned short)b;
        atomicAdd(&cnt[b], 1);               // LDS atomic
    }
    __syncthreads();

    for (int j = t; j < NB; j += 256) {
        int c = cnt[j];
        if (c > 0) base_l[j] = atomicAdd(&bcur[j], c);   // one per bucket
    }
    __syncthreads();

    for (int i = t; i < nE; i += 256) {
        int b = bb[i];
        int p = atomicAdd(&cnt2[b], 1);      // LDS atomic
        ebuf[base_l[b] + p] = pk[i];
    }
}

// ---------------------------------------------------------------------------
// Exclusive scan of the 512 final bucket counts -> gbase (single block).
// ---------------------------------------------------------------------------
__global__ __launch_bounds__(512) void scan_buckets(const int* __restrict__ bcur,
                                                    int* __restrict__ gbase,
                                                    int* __restrict__ rowptr) {
    __shared__ int tmp[512];
    int t = threadIdx.x;
    int c = bcur[t] - t * CAP;               // this bucket's edge count
    tmp[t] = c;
    __syncthreads();
    for (int off = 1; off < 512; off <<= 1) {
        int x = 0;
        if (t >= off) x = tmp[t - off];
        __syncthreads();
        if (t >= off) tmp[t] += x;
        __syncthreads();
    }
    gbase[t] = tmp[t] - c;                   // exclusive
    if (t == 511) rowptr[N_NODES] = N_EDGES;
}

// ---------------------------------------------------------------------------
// Per-bucket finalize: local dst histogram -> dinv, local scan -> rowptr,
// LDS scatter -> coalesced col.
// ---------------------------------------------------------------------------
__global__ __launch_bounds__(256) void fill_csr3(
    const int* __restrict__ bcur,
    const int* __restrict__ gbase,
    const unsigned int* __restrict__ ebuf,
    int* __restrict__ rowptr,
    float* __restrict__ dinv,
    int* __restrict__ col) {
    __shared__ int lhist[NPB];
    __shared__ int lrow[NPB];      // exclusive offsets, then scatter cursors
    __shared__ int tmp[256];
    __shared__ int lbuf[CAP];      // 32 KB
    int b = blockIdx.x;
    int t = threadIdx.x;
    int n0 = b * NPB;  if (n0 > N_NODES) n0 = N_NODES;
    int n1 = n0 + NPB; if (n1 > N_NODES) n1 = N_NODES;
    int nn  = n1 - n0;
    int cnt = bcur[b] - b * CAP;
    int E0  = gbase[b];
    const unsigned int* reg = ebuf + (size_t)b * CAP;

    for (int j = t; j < NPB; j += 256) lhist[j] = 0;
    __syncthreads();
    for (int i = t; i < cnt; i += 256)
        atomicAdd(&lhist[reg[i] & 255u], 1);     // LDS histogram
    __syncthreads();

    // fused make_dinv (self-loop +1)
    for (int j = t; j < nn; j += 256)
        dinv[n0 + j] = rsqrtf((float)(lhist[j] + 1));

    // exclusive scan of lhist[0..nn) (NPB < 256: one Hillis-Steele pass)
    int v = (t < NPB) ? lhist[t] : 0;
    tmp[t] = v;
    __syncthreads();
    for (int off = 1; off < 256; off <<= 1) {
        int x = 0;
        if (t >= off) x = tmp[t - off];
        __syncthreads();
        if (t >= off) tmp[t] += x;
        __syncthreads();
    }
    if (t < NPB) lrow[t] = tmp[t] - v;
    __syncthreads();

    for (int j = t; j < nn; j += 256)
        rowptr[n0 + j] = E0 + lrow[j];
    __syncthreads();               // rowptr reads lrow before cursor mutation

    for (int i = t; i < cnt; i += 256) {
        unsigned int e = reg[i];
        int p = atomicAdd(&lrow[e & 255u], 1);
        lbuf[p] = (int)(e >> 8);
    }
    __syncthreads();
    for (int j = t; j < cnt; j += 256)
        col[E0 + j] = lbuf[j];
}

// ---------------------------------------------------------------------------
// GEMM1: h1b[n][c2] = pack_bf16( (x[n]·W1[:,2c2..2c2+1]) * dinv[n] )
// ---------------------------------------------------------------------------
__global__ __launch_bounds__(256) void gemm1_scale(
    const float* __restrict__ x,
    const float* __restrict__ W1,
    const float* __restrict__ dinv,
    unsigned int* __restrict__ h1b) {
    __shared__ float w[IN_CH * HID];   // 16 KB
    for (int i = threadIdx.x; i < IN_CH * HID; i += 256)
        w[i] = W1[i];
    __syncthreads();

    int node = blockIdx.x * 8 + (threadIdx.x >> 5);
    int c    = threadIdx.x & 31;
    if (node >= N_NODES) return;

    const float4* xr = reinterpret_cast<const float4*>(x + (size_t)node * IN_CH);
    float acc = 0.0f;
#pragma unroll
    for (int k4 = 0; k4 < IN_CH / 4; ++k4) {
        float4 v = xr[k4];
        acc += v.x * w[(k4 * 4 + 0) * HID + c]
             + v.y * w[(k4 * 4 + 1) * HID + c]
             + v.z * w[(k4 * 4 + 2) * HID + c]
             + v.w * w[(k4 * 4 + 3) * HID + c];
    }
    float val = acc * dinv[node];
    int c2 = c & 15;
    float lo = __shfl(val, 2 * c2, 32);
    float hi = __shfl(val, 2 * c2 + 1, 32);
    if (c < 16) h1b[(size_t)node * 16 + c2] = pack_bf16x2(lo, hi);
}

// ---------------------------------------------------------------------------
// Layer-1 aggregate (bf16 gather table, 2 edges x 16 lanes per 32-group,
// 4-deep unroll = 8 gathers in flight) + relu + gemm2 (shuffles) -> h3b.
// ---------------------------------------------------------------------------
__global__ __launch_bounds__(256) void aggregate1(
    const int* __restrict__ rowptr,
    const int* __restrict__ col,
    const unsigned int* __restrict__ h1b,
    const float* __restrict__ dinv,
    const float* __restrict__ b1,
    const float* __restrict__ W2,
    unsigned int* __restrict__ h3b) {
    __shared__ float w2s[HID * HID];   // 4 KB
    for (int i = threadIdx.x; i < HID * HID; i += 256)
        w2s[i] = W2[i];
    __syncthreads();

    int node = blockIdx.x * 8 + (threadIdx.x >> 5);
    int lane = threadIdx.x & 31;
    if (node >= N_NODES) return;
    int half = lane >> 4;
    int c2   = lane & 15;

    int e0 = rowptr[node];
    int e1 = rowptr[node + 1];
    float ae0 = 0.f, ao0 = 0.f, ae1 = 0.f, ao1 = 0.f;
    float ae2 = 0.f, ao2 = 0.f, ae3 = 0.f, ao3 = 0.f;
    if (half == 0) {                       // self-loop
        unsigned int sv = h1b[(size_t)node * 16 + c2];
        ae0 = bf_lo(sv); ao0 = bf_hi(sv);
    }
    int ee = e0 + half;
    for (; ee + 6 < e1; ee += 8) {
        int s0 = col[ee], s1 = col[ee + 2], s2 = col[ee + 4], s3 = col[ee + 6];
        unsigned int v0 = h1b[(size_t)s0 * 16 + c2];
        unsigned int v1 = h1b[(size_t)s1 * 16 + c2];
        unsigned int v2 = h1b[(size_t)s2 * 16 + c2];
        unsigned int v3 = h1b[(size_t)s3 * 16 + c2];
        ae0 += bf_lo(v0); ao0 += bf_hi(v0);
        ae1 += bf_lo(v1); ao1 += bf_hi(v1);
        ae2 += bf_lo(v2); ao2 += bf_hi(v2);
        ae3 += bf_lo(v3); ao3 += bf_hi(v3);
    }
    for (; ee < e1; ee += 2) {
        unsigned int v = h1b[(size_t)col[ee] * 16 + c2];
        ae1 += bf_lo(v); ao1 += bf_hi(v);
    }
    float ae = (ae0 + ae1) + (ae2 + ae3);
    float ao = (ao0 + ao1) + (ao2 + ao3);
    ae += __shfl_xor(ae, 16, 32);          // combine halves
    ao += __shfl_xor(ao, 16, 32);

    float dn = dinv[node];
    float h2e = ae * dn + b1[2 * c2];      h2e = h2e > 0.f ? h2e : 0.f;
    float h2o = ao * dn + b1[2 * c2 + 1];  h2o = h2o > 0.f ? h2o : 0.f;

    // gemm2: lane j (half 0) holds h2[2j], h2[2j+1]; all-to-all via shfl
    float a2e = 0.f, a2o = 0.f;
#pragma unroll
    for (int j = 0; j < 16; ++j) {
        float he = __shfl(h2e, j, 32);     // h2[2j]
        float ho = __shfl(h2o, j, 32);     // h2[2j+1]
        a2e += he * w2s[(2 * j) * HID + 2 * c2]     + ho * w2s[(2 * j + 1) * HID + 2 * c2];
        a2o += he * w2s[(2 * j) * HID + 2 * c2 + 1] + ho * w2s[(2 * j + 1) * HID + 2 * c2 + 1];
    }
    if (half == 0)
        h3b[(size_t)node * 16 + c2] = pack_bf16x2(a2e * dn, a2o * dn);
}

// ---------------------------------------------------------------------------
// Layer-2 aggregate (bf16 gather) + epilogue2 -> f32 out
// ---------------------------------------------------------------------------
__global__ __launch_bounds__(256) void aggregate2(
    const int* __restrict__ rowptr,
    const int* __restrict__ col,
    const unsigned int* __restrict__ h3b,
    const float* __restrict__ dinv,
    const float* __restrict__ b2,
    float2* __restrict__ out2) {
    int node = blockIdx.x * 8 + (threadIdx.x >> 5);
    int lane = threadIdx.x & 31;
    if (node >= N_NODES) return;
    int half = lane >> 4;
    int c2   = lane & 15;

    int e0 = rowptr[node];
    int e1 = rowptr[node + 1];
    float ae0 = 0.f, ao0 = 0.f, ae1 = 0.f, ao1 = 0.f;
    float ae2 = 0.f, ao2 = 0.f, ae3 = 0.f, ao3 = 0.f;
    if (half == 0) {                       // self-loop
        unsigned int sv = h3b[(size_t)node * 16 + c2];
        ae0 = bf_lo(sv); ao0 = bf_hi(sv);
    }
    int ee = e0 + half;
    for (; ee + 6 < e1; ee += 8) {
        int s0 = col[ee], s1 = col[ee + 2], s2 = col[ee + 4], s3 = col[ee + 6];
        unsigned int v0 = h3b[(size_t)s0 * 16 + c2];
        unsigned int v1 = h3b[(size_t)s1 * 16 + c2];
        unsigned int v2 = h3b[(size_t)s2 * 16 + c2];
        unsigned int v3 = h3b[(size_t)s3 * 16 + c2];
        ae0 += bf_lo(v0); ao0 += bf_hi(v0);
        ae1 += bf_lo(v1); ao1 += bf_hi(v1);
        ae2 += bf_lo(v2); ao2 += bf_hi(v2);
        ae3 += bf_lo(v3); ao3 += bf_hi(v3);
    }
    for (; ee < e1; ee += 2) {
        unsigned int v = h3b[(size_t)col[ee] * 16 + c2];
        ae1 += bf_lo(v); ao1 += bf_hi(v);
    }
    float ae = (ae0 + ae1) + (ae2 + ae3);
    float ao = (ao0 + ao1) + (ao2 + ao3);
    ae += __shfl_xor(ae, 16, 32);
    ao += __shfl_xor(ao, 16, 32);

    if (half == 0) {
        float dn = dinv[node];
        float2 o;
        o.x = ae * dn + b2[2 * c2];
        o.y = ao * dn + b2[2 * c2 + 1];
        out2[(size_t)node * 16 + c2] = o;
    }
}

// ---------------------------------------------------------------------------
extern "C" void kernel_launch(void* const* d_in, const int* in_sizes, int n_in,
                              void* d_out, int out_size, void* d_ws, size_t ws_size,
                              hipStream_t stream) {
    const float* x  = (const float*)d_in[0];
    const int*   ei = (const int*)d_in[1];
    const float* W1 = (const float*)d_in[2];
    const float* b1 = (const float*)d_in[3];
    const float* W2 = (const float*)d_in[4];
    const float* b2 = (const float*)d_in[5];
    float* out = (float*)d_out;

    // workspace: flag[64] | bcur[512] | gbase[512] | rowptr[N+1] | col[E] |
    //            dinv[N] | region{ h1b (6.4MB) | h3b (6.4MB) } where ebuf
    //            (512*CAP u32 = 16 MiB) ALIASES the region (dead by gemm1).
    // Total ~31 MiB.
    int*          flag   = (int*)d_ws;
    int*          bcur   = flag + 64;
    int*          gbase  = bcur + NB;
    int*          rowptr = gbase + NB;
    int*          col    = rowptr + (N_NODES + 1);
    float*        dinv   = (float*)(col + N_EDGES);
    unsigned int* h1b    = (unsigned int*)(dinv + N_NODES);
    unsigned int* h3b    = h1b + (size_t)N_NODES * 16;
    unsigned int* ebuf   = h1b;                          // alias, dead by gemm1

    const int gemmBlocks  = (N_NODES + 7) / 8;               // 12500
    const int chunkBlocks = (N_EDGES + CHUNK - 1) / CHUNK;   // 391

    detect_idx<<<1, 256, 0, stream>>>(ei, flag);

    // bucketed CSR build (single pass over edge_index)
    bcur_init<<<(NB + 255) / 256, 256, 0, stream>>>(bcur);
    bucket_scatter2<<<chunkBlocks, 256, 0, stream>>>(ei, flag, bcur, ebuf);
    scan_buckets<<<1, 512, 0, stream>>>(bcur, gbase, rowptr);
    fill_csr3<<<NB, 256, 0, stream>>>(bcur, gbase, ebuf, rowptr, dinv, col);

    // layer 1 (+ fused relu + gemm2)
    gemm1_scale<<<gemmBlocks, 256, 0, stream>>>(x, W1, dinv, h1b);
    aggregate1<<<gemmBlocks, 256, 0, stream>>>(rowptr, col, h1b, dinv, b1, W2, h3b);

    // layer 2 (+ fused epilogue)
    aggregate2<<<gemmBlocks, 256, 0, stream>>>(rowptr, col, h3b, dinv, b2, (float2*)out);
}